// Round 5
// baseline (624.934 us; speedup 1.0000x reference)
//
#include <hip/hip_runtime.h>
#include <hip/hip_bf16.h>

#define N_HID 128
#define BSH 9
#define BNODES 512          // nodes per bucket (1 << BSH)
#define CAP 14848           // LDS colx staging cap per bucket (58 KB)
#define CHUNK 4096          // edges per k_bucket block

typedef int   vint4  __attribute__((ext_vector_type(4)));
typedef float vflt4  __attribute__((ext_vector_type(4)));

// ---------------- bucketed CSR build ----------------

// zero gcount (block 0) + dummy Hs row n (block 1)
__global__ void k_init(int* gcount, int nbk, float* HHrow) {
    if (blockIdx.x == 0) {
        int i = threadIdx.x;
        if (i < nbk) gcount[i] = 0;
    } else {
        if (threadIdx.x < N_HID) HHrow[threadIdx.x] = 0.f;
    }
}

// count edges per dst-bucket (LDS-privatized)
__global__ __launch_bounds__(256) void k_bcount(const int* __restrict__ dst,
                                                int E, int n, int* __restrict__ gcount) {
    __shared__ int hist[256];
    int t = threadIdx.x;
    hist[t] = 0;
    __syncthreads();
    long base = (long)blockIdx.x * CHUNK;
    long T = (long)E + n;
    int cnt = (int)min((long)CHUNK, T - base);
    for (int j = t; j < cnt; j += 256) {
        long i = base + j;
        int d = (i < E) ? dst[i] : (int)(i - E);
        atomicAdd(&hist[d >> BSH], 1);
    }
    __syncthreads();
    if (hist[t] > 0) atomicAdd(&gcount[t], hist[t]);
}

// exclusive scan of bucket counts -> gbase0, init gcur
__global__ void k_bscan(const int* __restrict__ gcount, int* __restrict__ gbase0,
                        int* __restrict__ gcur, int nbk) {
    __shared__ int s[256];
    int t = threadIdx.x;
    int v = (t < nbk) ? gcount[t] : 0;
    s[t] = v;
    __syncthreads();
    for (int off = 1; off < 256; off <<= 1) {
        int y = (t >= off) ? s[t - off] : 0;
        __syncthreads();
        s[t] += y;
        __syncthreads();
    }
    if (t < nbk) { gbase0[t] = s[t] - v; gcur[t] = s[t] - v; }
}

// partition edges into bucket-contiguous bpair[] (packed u32: src<<9 | dst_local)
__global__ __launch_bounds__(256) void k_bucket(const int* __restrict__ src,
                                                const int* __restrict__ dst,
                                                int E, int n, int* __restrict__ gcur,
                                                unsigned* __restrict__ bpair) {
    __shared__ int hist[256];
    __shared__ int incl[256];
    __shared__ int loff[256];
    __shared__ int gb[256];
    __shared__ unsigned lp[CHUNK];
    __shared__ unsigned char pb[CHUNK];
    int t = threadIdx.x;
    hist[t] = 0;
    __syncthreads();
    long base = (long)blockIdx.x * CHUNK;
    long T = (long)E + n;
    int cnt = (int)min((long)CHUNK, T - base);

    unsigned w_[16];
    int b_[16], r_[16];
    #pragma unroll
    for (int u = 0; u < 16; ++u) {
        int j = t + u * 256;
        if (j < cnt) {
            long i = base + j;
            int s, d;
            if (i < E) { s = src[i]; d = dst[i]; } else { s = (int)(i - E); d = s; }
            w_[u] = ((unsigned)s << BSH) | (unsigned)(d & (BNODES - 1));
            b_[u] = d >> BSH;
            r_[u] = atomicAdd(&hist[b_[u]], 1);
        } else { w_[u] = 0; b_[u] = 0; r_[u] = -1; }
    }
    __syncthreads();
    incl[t] = hist[t];
    __syncthreads();
    for (int off = 1; off < 256; off <<= 1) {
        int y = (t >= off) ? incl[t - off] : 0;
        __syncthreads();
        incl[t] += y;
        __syncthreads();
    }
    loff[t] = incl[t] - hist[t];
    if (hist[t] > 0) gb[t] = atomicAdd(&gcur[t], hist[t]);
    __syncthreads();
    #pragma unroll
    for (int u = 0; u < 16; ++u) {
        if (r_[u] >= 0) {
            int p = loff[b_[u]] + r_[u];
            lp[p] = w_[u];
            pb[p] = (unsigned char)b_[u];
        }
    }
    __syncthreads();
    for (int p = t; p < cnt; p += 256) {
        int b = pb[p];
        bpair[(size_t)gb[b] + (p - loff[b])] = lp[p];
    }
}

// per-bucket: degree hist -> dinv, local padded-offset scan -> lofs, bucket total -> psum
__global__ __launch_bounds__(256) void k_bdeg(const unsigned* __restrict__ bpair,
                                              const int* __restrict__ gbase0,
                                              const int* __restrict__ gcount,
                                              float* __restrict__ dinv,
                                              int* __restrict__ lofs,
                                              int* __restrict__ psum, int n) {
    __shared__ int hist[BNODES];
    __shared__ int sc[256];
    int b = blockIdx.x, t = threadIdx.x;
    hist[t] = 0; hist[t + 256] = 0;
    __syncthreads();
    int gs = gbase0[b], ge = gs + gcount[b];
    for (int e = gs + t; e < ge; e += 256)
        atomicAdd(&hist[bpair[e] & (BNODES - 1)], 1);
    __syncthreads();
    int q0 = 2 * t, q1 = 2 * t + 1;
    int p0 = (hist[q0] + 3) & ~3;
    int p1 = (hist[q1] + 3) & ~3;
    int pair = p0 + p1;
    sc[t] = pair;
    __syncthreads();
    for (int off = 1; off < 256; off <<= 1) {
        int y = (t >= off) ? sc[t - off] : 0;
        __syncthreads();
        sc[t] += y;
        __syncthreads();
    }
    int excl = sc[t] - pair;
    int first = b << BSH;
    if (first + q0 < n) {
        lofs[first + q0] = excl;
        dinv[first + q0] = rsqrtf((float)hist[q0]);
    }
    if (first + q1 < n) {
        lofs[first + q1] = excl + p0;
        dinv[first + q1] = rsqrtf((float)hist[q1]);
    }
    if (t == 255) psum[b] = sc[255];
}

// scan bucket padded totals -> pbase; write rptr[n]
__global__ void k_pscan(const int* __restrict__ psum, int* __restrict__ pbase,
                        int* __restrict__ rptr, int n, int nbk) {
    __shared__ int s[256];
    int t = threadIdx.x;
    int v = (t < nbk) ? psum[t] : 0;
    s[t] = v;
    __syncthreads();
    for (int off = 1; off < 256; off <<= 1) {
        int y = (t >= off) ? s[t - off] : 0;
        __syncthreads();
        s[t] += y;
        __syncthreads();
    }
    if (t < nbk) pbase[t] = s[t] - v;
    if (t == nbk - 1) rptr[n] = s[t];
}

// per-bucket CSR fill: LDS scatter (pad slots -> dummy node n), write rptr + colx
__global__ __launch_bounds__(256) void k_bfill(const unsigned* __restrict__ bpair,
                                               const int* __restrict__ gbase0,
                                               const int* __restrict__ gcount,
                                               const int* __restrict__ pbase,
                                               const int* __restrict__ lofs,
                                               const int* __restrict__ psum,
                                               int* __restrict__ rptr,
                                               int* __restrict__ colx, int n) {
    __shared__ int cur[BNODES];
    __shared__ int lcol[CAP];
    int b = blockIdx.x, t = threadIdx.x;
    int first = b << BSH;
    int base = pbase[b];
    int tot = min(psum[b], CAP);
    int lim = min(BNODES, n - first);
    for (int q = t; q < lim; q += 256) {
        int lo = lofs[first + q];
        cur[q] = lo;
        rptr[first + q] = base + lo;
    }
    for (int p = t; p < tot; p += 256) lcol[p] = n;
    __syncthreads();
    int gs = gbase0[b], ge = gs + gcount[b];
    for (int e = gs + t; e < ge; e += 256) {
        unsigned w = bpair[e];
        int lpos = atomicAdd(&cur[w & (BNODES - 1)], 1);
        if (lpos < CAP) lcol[lpos] = (int)(w >> BSH);
    }
    __syncthreads();
    for (int p = t; p < tot; p += 256) colx[base + p] = lcol[p];
}

// ---------------- dense GEMM: Hs[M x 128] = scale[.] * (A[M x 128] @ W[128 x 128]) --------

__global__ __launch_bounds__(256) void k_gemm(const float* __restrict__ A,
                                              const float* __restrict__ W,
                                              const float* __restrict__ scale,
                                              float* __restrict__ C, int M) {
    __shared__ float As[32][132];
    __shared__ float Ws[32 * 128];   // repacked: [kk][h(2)][tx(16)][j(4)]
    int tid = threadIdx.x;
    int tx = tid & 15;
    int ty = tid >> 4;
    int bm = blockIdx.x * 128;
    float acc[8][8] = {};

    for (int k0 = 0; k0 < 128; k0 += 32) {
        #pragma unroll
        for (int it = 0; it < 4; ++it) {
            int idx = it * 256 + tid;
            int row = idx >> 3;
            int kq  = idx & 7;
            int grow = bm + row;
            float4 v = make_float4(0.f, 0.f, 0.f, 0.f);
            if (grow < M) v = *(const float4*)(A + (size_t)grow * 128 + k0 + kq * 4);
            As[kq * 4 + 0][row] = v.x;
            As[kq * 4 + 1][row] = v.y;
            As[kq * 4 + 2][row] = v.z;
            As[kq * 4 + 3][row] = v.w;
        }
        #pragma unroll
        for (int it = 0; it < 4; ++it) {
            int idx = it * 256 + tid;
            int kk = idx >> 5;
            int q  = idx & 31;
            float4 v = *(const float4*)(W + (size_t)(k0 + kk) * 128 + q * 4);
            *(float4*)&Ws[kk * 128 + ((q & 1) << 6) + ((q >> 1) << 2)] = v;
        }
        __syncthreads();
        #pragma unroll
        for (int kk = 0; kk < 32; ++kk) {
            float a[8], w[8];
            *(float4*)&a[0] = *(const float4*)&As[kk][ty * 8];
            *(float4*)&a[4] = *(const float4*)&As[kk][ty * 8 + 4];
            *(float4*)&w[0] = *(const float4*)&Ws[kk * 128 + tx * 4];
            *(float4*)&w[4] = *(const float4*)&Ws[kk * 128 + 64 + tx * 4];
            #pragma unroll
            for (int i = 0; i < 8; ++i)
                #pragma unroll
                for (int j = 0; j < 8; ++j)
                    acc[i][j] = fmaf(a[i], w[j], acc[i][j]);
        }
        __syncthreads();
    }
    #pragma unroll
    for (int i = 0; i < 8; ++i) {
        int grow = bm + ty * 8 + i;
        if (grow < M) {
            float di = scale[grow];
            float4 o0, o1;
            o0.x = acc[i][0] * di; o0.y = acc[i][1] * di;
            o0.z = acc[i][2] * di; o0.w = acc[i][3] * di;
            o1.x = acc[i][4] * di; o1.y = acc[i][5] * di;
            o1.z = acc[i][6] * di; o1.w = acc[i][7] * di;
            *(float4*)(C + (size_t)grow * 128 + tx * 8)     = o0;
            *(float4*)(C + (size_t)grow * 128 + tx * 8 + 4) = o1;
        }
    }
}

// ---------------- SpMM aggregate: 2 nodes per half-wave, 8 gathers in flight ----------------

__global__ __launch_bounds__(256) void k_spmm(const float* __restrict__ Hs,
                                              const int* __restrict__ colx,
                                              const int* __restrict__ rptr,
                                              const float* __restrict__ dinv,
                                              const float* __restrict__ bias,
                                              float* __restrict__ out,
                                              int n, int do_relu) {
    int q = blockIdx.x * 8 + (threadIdx.x >> 5);
    int na = q * 2;
    if (na >= n) return;
    int nb2 = na + 1;
    int lane = threadIdx.x & 31;
    const int c = lane * 4;
    const float* Hc = Hs + c;
    int ea = rptr[na],  e1a = rptr[na + 1];
    int eb = rptr[nb2], e1b = rptr[nb2 + 1];
    int la = e1a - ea, lb = e1b - eb;
    int cm = (la < lb) ? la : lb;
    vflt4 A = {0.f, 0.f, 0.f, 0.f};
    vflt4 B = {0.f, 0.f, 0.f, 0.f};
    int k = 0;
    #pragma unroll 1
    for (; k < cm; k += 4) {
        vint4 sa = __builtin_nontemporal_load((const vint4*)(colx + ea + k));
        vint4 sb = __builtin_nontemporal_load((const vint4*)(colx + eb + k));
        vflt4 a0 = *(const vflt4*)(Hc + (sa.x << 7));
        vflt4 a1 = *(const vflt4*)(Hc + (sa.y << 7));
        vflt4 a2 = *(const vflt4*)(Hc + (sa.z << 7));
        vflt4 a3 = *(const vflt4*)(Hc + (sa.w << 7));
        vflt4 b0 = *(const vflt4*)(Hc + (sb.x << 7));
        vflt4 b1 = *(const vflt4*)(Hc + (sb.y << 7));
        vflt4 b2 = *(const vflt4*)(Hc + (sb.z << 7));
        vflt4 b3 = *(const vflt4*)(Hc + (sb.w << 7));
        A += (a0 + a1) + (a2 + a3);
        B += (b0 + b1) + (b2 + b3);
    }
    #pragma unroll 1
    for (; k < la; k += 4) {
        vint4 sa = __builtin_nontemporal_load((const vint4*)(colx + ea + k));
        vflt4 a0 = *(const vflt4*)(Hc + (sa.x << 7));
        vflt4 a1 = *(const vflt4*)(Hc + (sa.y << 7));
        vflt4 a2 = *(const vflt4*)(Hc + (sa.z << 7));
        vflt4 a3 = *(const vflt4*)(Hc + (sa.w << 7));
        A += (a0 + a1) + (a2 + a3);
    }
    int k2 = cm;
    #pragma unroll 1
    for (; k2 < lb; k2 += 4) {
        vint4 sb = __builtin_nontemporal_load((const vint4*)(colx + eb + k2));
        vflt4 b0 = *(const vflt4*)(Hc + (sb.x << 7));
        vflt4 b1 = *(const vflt4*)(Hc + (sb.y << 7));
        vflt4 b2 = *(const vflt4*)(Hc + (sb.z << 7));
        vflt4 b3 = *(const vflt4*)(Hc + (sb.w << 7));
        B += (b0 + b1) + (b2 + b3);
    }
    vflt4 bv = *(const vflt4*)(bias + c);
    float da = dinv[na], db = dinv[nb2];
    vflt4 oa = A * da + bv;
    vflt4 ob = B * db + bv;
    if (do_relu) {
        oa = __builtin_elementwise_max(oa, (vflt4){0.f, 0.f, 0.f, 0.f});
        ob = __builtin_elementwise_max(ob, (vflt4){0.f, 0.f, 0.f, 0.f});
    }
    __builtin_nontemporal_store(oa, (vflt4*)(out + (size_t)na  * 128 + c));
    __builtin_nontemporal_store(ob, (vflt4*)(out + (size_t)nb2 * 128 + c));
}

// ---------------- host ----------------

extern "C" void kernel_launch(void* const* d_in, const int* in_sizes, int n_in,
                              void* d_out, int out_size, void* d_ws, size_t ws_size,
                              hipStream_t stream) {
    const float* x  = (const float*)d_in[0];
    const int*   ei = (const int*)d_in[1];
    const float* W1 = (const float*)d_in[2];
    const float* b1 = (const float*)d_in[3];
    const float* W2 = (const float*)d_in[4];
    const float* b2 = (const float*)d_in[5];
    const float* W3 = (const float*)d_in[6];
    const float* b3 = (const float*)d_in[7];
    float* out = (float*)d_out;

    const int n = in_sizes[0] / N_HID;       // 100000
    const int E = in_sizes[1] / 2;           // 1600000
    const long T = (long)E + n;

    const int* src = ei;
    const int* dst = ei + E;

    size_t off = 0;
    auto alloc = [&](size_t bytes) {
        size_t o = off;
        off += (bytes + 255) & ~(size_t)255;
        return (char*)d_ws + o;
    };
    float* dinv   = (float*)alloc((size_t)n * 4);
    int*   rptr   = (int*)  alloc((size_t)(n + 1) * 4);
    int*   lofs   = (int*)  alloc((size_t)n * 4);
    int*   gcount = (int*)  alloc(1024);
    int*   gbase0 = (int*)  alloc(1024);
    int*   gcur   = (int*)  alloc(1024);
    int*   psum   = (int*)  alloc(1024);
    int*   pbase  = (int*)  alloc(1024);
    int*   colx   = (int*)  alloc((size_t)(T + 3 * (size_t)n + 64) * 4);
    float* HH     = (float*)alloc((size_t)(n + 1) * N_HID * 4);  // +1 dummy zero row
    // bpair (u32, 6.8 MB) aliases HH's front (consumed by k_bfill before gemm1 writes HH)
    unsigned* bpair = (unsigned*)HH;
    (void)ws_size;

    const int NBK  = (n + BNODES - 1) >> BSH;          // 196 buckets
    const int ABLK = (int)((T + CHUNK - 1) / CHUNK);   // 416 chunks

    k_init<<<2, 256, 0, stream>>>(gcount, NBK, HH + (size_t)n * N_HID);
    k_bcount<<<ABLK, 256, 0, stream>>>(dst, E, n, gcount);
    k_bscan<<<1, 256, 0, stream>>>(gcount, gbase0, gcur, NBK);
    k_bucket<<<ABLK, 256, 0, stream>>>(src, dst, E, n, gcur, bpair);
    k_bdeg<<<NBK, 256, 0, stream>>>(bpair, gbase0, gcount, dinv, lofs, psum, n);
    k_pscan<<<1, 256, 0, stream>>>(psum, pbase, rptr, n, NBK);
    k_bfill<<<NBK, 256, 0, stream>>>(bpair, gbase0, gcount, pbase, lofs, psum, rptr, colx, n);

    int gblk = (n + 127) / 128;
    int sblk = (n / 2 + 7) / 8;    // half-wave per 2 nodes, 8 half-waves/block

    k_gemm<<<gblk, 256, 0, stream>>>(x, W1, dinv, HH, n);
    k_spmm<<<sblk, 256, 0, stream>>>(HH, colx, rptr, dinv, b1, out, n, 1);
    k_gemm<<<gblk, 256, 0, stream>>>(out, W2, dinv, HH, n);
    k_spmm<<<sblk, 256, 0, stream>>>(HH, colx, rptr, dinv, b2, out, n, 1);
    k_gemm<<<gblk, 256, 0, stream>>>(out, W3, dinv, HH, n);
    k_spmm<<<sblk, 256, 0, stream>>>(HH, colx, rptr, dinv, b3, out, n, 0);
}

// Round 6
// 614.086 us; speedup vs baseline: 1.0177x; 1.0177x over previous
//
#include <hip/hip_runtime.h>
#include <hip/hip_bf16.h>

#define N_HID 128
#define BSH 9
#define BNODES 512          // nodes per bucket (1 << BSH)
#define CAP 14848           // LDS colx staging cap per bucket (58 KB)
#define CHUNK 4096          // edges per k_bucket block
#define NCHUNK 8            // feature chunks (16 cols each) == XCD count

typedef int   vint4  __attribute__((ext_vector_type(4)));
typedef float vflt4  __attribute__((ext_vector_type(4)));

// ---------------- bucketed CSR build ----------------

// zero gcount (block 0) + dummy rows of chunked activation buffers (blocks 1,2)
__global__ void k_init(int* gcount, int nbk, float* HHc, float* actD, float* actS,
                       int n, size_t PS) {
    int t = threadIdx.x;
    if (blockIdx.x == 0) {
        if (t < nbk) gcount[t] = 0;
    } else if (blockIdx.x == 1) {
        if (t < 128) {  // 8 planes x 16
            int p = t >> 4, l = t & 15;
            HHc[(size_t)p * PS + (size_t)n * 16 + l] = 0.f;
        }
    } else {
        if (t < 128) {
            int p = t >> 4, l = t & 15;
            float* base = (p < 7) ? (actD + (size_t)p * PS) : actS;
            base[(size_t)n * 16 + l] = 0.f;
        }
    }
}

// count edges per dst-bucket (LDS-privatized)
__global__ __launch_bounds__(256) void k_bcount(const int* __restrict__ dst,
                                                int E, int n, int* __restrict__ gcount) {
    __shared__ int hist[256];
    int t = threadIdx.x;
    hist[t] = 0;
    __syncthreads();
    long base = (long)blockIdx.x * CHUNK;
    long T = (long)E + n;
    int cnt = (int)min((long)CHUNK, T - base);
    for (int j = t; j < cnt; j += 256) {
        long i = base + j;
        int d = (i < E) ? dst[i] : (int)(i - E);
        atomicAdd(&hist[d >> BSH], 1);
    }
    __syncthreads();
    if (hist[t] > 0) atomicAdd(&gcount[t], hist[t]);
}

// exclusive scan of bucket counts -> gbase0, init gcur
__global__ void k_bscan(const int* __restrict__ gcount, int* __restrict__ gbase0,
                        int* __restrict__ gcur, int nbk) {
    __shared__ int s[256];
    int t = threadIdx.x;
    int v = (t < nbk) ? gcount[t] : 0;
    s[t] = v;
    __syncthreads();
    for (int off = 1; off < 256; off <<= 1) {
        int y = (t >= off) ? s[t - off] : 0;
        __syncthreads();
        s[t] += y;
        __syncthreads();
    }
    if (t < nbk) { gbase0[t] = s[t] - v; gcur[t] = s[t] - v; }
}

// partition edges into bucket-contiguous bpair[] (packed u32: src<<9 | dst_local)
__global__ __launch_bounds__(256) void k_bucket(const int* __restrict__ src,
                                                const int* __restrict__ dst,
                                                int E, int n, int* __restrict__ gcur,
                                                unsigned* __restrict__ bpair) {
    __shared__ int hist[256];
    __shared__ int incl[256];
    __shared__ int loff[256];
    __shared__ int gb[256];
    __shared__ unsigned lp[CHUNK];
    __shared__ unsigned char pb[CHUNK];
    int t = threadIdx.x;
    hist[t] = 0;
    __syncthreads();
    long base = (long)blockIdx.x * CHUNK;
    long T = (long)E + n;
    int cnt = (int)min((long)CHUNK, T - base);

    unsigned w_[16];
    int b_[16], r_[16];
    #pragma unroll
    for (int u = 0; u < 16; ++u) {
        int j = t + u * 256;
        if (j < cnt) {
            long i = base + j;
            int s, d;
            if (i < E) { s = src[i]; d = dst[i]; } else { s = (int)(i - E); d = s; }
            w_[u] = ((unsigned)s << BSH) | (unsigned)(d & (BNODES - 1));
            b_[u] = d >> BSH;
            r_[u] = atomicAdd(&hist[b_[u]], 1);
        } else { w_[u] = 0; b_[u] = 0; r_[u] = -1; }
    }
    __syncthreads();
    incl[t] = hist[t];
    __syncthreads();
    for (int off = 1; off < 256; off <<= 1) {
        int y = (t >= off) ? incl[t - off] : 0;
        __syncthreads();
        incl[t] += y;
        __syncthreads();
    }
    loff[t] = incl[t] - hist[t];
    if (hist[t] > 0) gb[t] = atomicAdd(&gcur[t], hist[t]);
    __syncthreads();
    #pragma unroll
    for (int u = 0; u < 16; ++u) {
        if (r_[u] >= 0) {
            int p = loff[b_[u]] + r_[u];
            lp[p] = w_[u];
            pb[p] = (unsigned char)b_[u];
        }
    }
    __syncthreads();
    for (int p = t; p < cnt; p += 256) {
        int b = pb[p];
        bpair[(size_t)gb[b] + (p - loff[b])] = lp[p];
    }
}

// per-bucket: degree hist -> dinv, local padded-offset scan -> lofs, bucket total -> psum
__global__ __launch_bounds__(256) void k_bdeg(const unsigned* __restrict__ bpair,
                                              const int* __restrict__ gbase0,
                                              const int* __restrict__ gcount,
                                              float* __restrict__ dinv,
                                              int* __restrict__ lofs,
                                              int* __restrict__ psum, int n) {
    __shared__ int hist[BNODES];
    __shared__ int sc[256];
    int b = blockIdx.x, t = threadIdx.x;
    hist[t] = 0; hist[t + 256] = 0;
    __syncthreads();
    int gs = gbase0[b], ge = gs + gcount[b];
    for (int e = gs + t; e < ge; e += 256)
        atomicAdd(&hist[bpair[e] & (BNODES - 1)], 1);
    __syncthreads();
    int q0 = 2 * t, q1 = 2 * t + 1;
    int p0 = (hist[q0] + 3) & ~3;
    int p1 = (hist[q1] + 3) & ~3;
    int pair = p0 + p1;
    sc[t] = pair;
    __syncthreads();
    for (int off = 1; off < 256; off <<= 1) {
        int y = (t >= off) ? sc[t - off] : 0;
        __syncthreads();
        sc[t] += y;
        __syncthreads();
    }
    int excl = sc[t] - pair;
    int first = b << BSH;
    if (first + q0 < n) {
        lofs[first + q0] = excl;
        dinv[first + q0] = rsqrtf((float)hist[q0]);
    }
    if (first + q1 < n) {
        lofs[first + q1] = excl + p0;
        dinv[first + q1] = rsqrtf((float)hist[q1]);
    }
    if (t == 255) psum[b] = sc[255];
}

// scan bucket padded totals -> pbase; write rptr[n]
__global__ void k_pscan(const int* __restrict__ psum, int* __restrict__ pbase,
                        int* __restrict__ rptr, int n, int nbk) {
    __shared__ int s[256];
    int t = threadIdx.x;
    int v = (t < nbk) ? psum[t] : 0;
    s[t] = v;
    __syncthreads();
    for (int off = 1; off < 256; off <<= 1) {
        int y = (t >= off) ? s[t - off] : 0;
        __syncthreads();
        s[t] += y;
        __syncthreads();
    }
    if (t < nbk) pbase[t] = s[t] - v;
    if (t == nbk - 1) rptr[n] = s[t];
}

// per-bucket CSR fill: LDS scatter (pad slots -> dummy node n), write rptr + colx
__global__ __launch_bounds__(256) void k_bfill(const unsigned* __restrict__ bpair,
                                               const int* __restrict__ gbase0,
                                               const int* __restrict__ gcount,
                                               const int* __restrict__ pbase,
                                               const int* __restrict__ lofs,
                                               const int* __restrict__ psum,
                                               int* __restrict__ rptr,
                                               int* __restrict__ colx, int n) {
    __shared__ int cur[BNODES];
    __shared__ int lcol[CAP];
    int b = blockIdx.x, t = threadIdx.x;
    int first = b << BSH;
    int base = pbase[b];
    int tot = min(psum[b], CAP);
    int lim = min(BNODES, n - first);
    for (int q = t; q < lim; q += 256) {
        int lo = lofs[first + q];
        cur[q] = lo;
        rptr[first + q] = base + lo;
    }
    for (int p = t; p < tot; p += 256) lcol[p] = n;
    __syncthreads();
    int gs = gbase0[b], ge = gs + gcount[b];
    for (int e = gs + t; e < ge; e += 256) {
        unsigned w = bpair[e];
        int lpos = atomicAdd(&cur[w & (BNODES - 1)], 1);
        if (lpos < CAP) lcol[lpos] = (int)(w >> BSH);
    }
    __syncthreads();
    for (int p = t; p < tot; p += 256) colx[base + p] = lcol[p];
}

// ---------------- dense GEMM: HHc[chunked] = scale[.] * (A @ W) ----------------
// AL=0: A row-major [M][128].  AL=1: A chunked planes (actD planes 0-6, actS plane 7).
// Output always chunked planes in HHc (stride PS), row n untouched (dummy zero row).

template<int AL>
__global__ __launch_bounds__(256) void k_gemm(const float* __restrict__ A,
                                              const float* __restrict__ actD,
                                              const float* __restrict__ actS,
                                              const float* __restrict__ W,
                                              const float* __restrict__ scale,
                                              float* __restrict__ HHc,
                                              int M, size_t PS) {
    __shared__ float As[32][132];
    __shared__ float Ws[32 * 128];   // repacked: [kk][h(2)][tx(16)][j(4)]
    int tid = threadIdx.x;
    int tx = tid & 15;
    int ty = tid >> 4;
    int bm = blockIdx.x * 128;
    float acc[8][8] = {};

    for (int k0 = 0; k0 < 128; k0 += 32) {
        #pragma unroll
        for (int it = 0; it < 4; ++it) {
            int idx = it * 256 + tid;
            int row = idx >> 3;
            int kq  = idx & 7;
            int grow = bm + row;
            vflt4 v = {0.f, 0.f, 0.f, 0.f};
            if (grow < M) {
                if (AL == 0) {
                    v = *(const vflt4*)(A + (size_t)grow * 128 + k0 + kq * 4);
                } else {
                    int kc = k0 + kq * 4;
                    int plane = kc >> 4;
                    const float* ab = (plane < 7) ? (actD + (size_t)plane * PS) : actS;
                    v = *(const vflt4*)(ab + (size_t)grow * 16 + (kc & 15));
                }
            }
            As[kq * 4 + 0][row] = v.x;
            As[kq * 4 + 1][row] = v.y;
            As[kq * 4 + 2][row] = v.z;
            As[kq * 4 + 3][row] = v.w;
        }
        #pragma unroll
        for (int it = 0; it < 4; ++it) {
            int idx = it * 256 + tid;
            int kk = idx >> 5;
            int q  = idx & 31;
            vflt4 v = *(const vflt4*)(W + (size_t)(k0 + kk) * 128 + q * 4);
            *(vflt4*)&Ws[kk * 128 + ((q & 1) << 6) + ((q >> 1) << 2)] = v;
        }
        __syncthreads();
        #pragma unroll
        for (int kk = 0; kk < 32; ++kk) {
            float a[8], w[8];
            *(vflt4*)&a[0] = *(const vflt4*)&As[kk][ty * 8];
            *(vflt4*)&a[4] = *(const vflt4*)&As[kk][ty * 8 + 4];
            *(vflt4*)&w[0] = *(const vflt4*)&Ws[kk * 128 + tx * 4];
            *(vflt4*)&w[4] = *(const vflt4*)&Ws[kk * 128 + 64 + tx * 4];
            #pragma unroll
            for (int i = 0; i < 8; ++i)
                #pragma unroll
                for (int j = 0; j < 8; ++j)
                    acc[i][j] = fmaf(a[i], w[j], acc[i][j]);
        }
        __syncthreads();
    }
    // epilogue: cols tx*8..tx*8+7 live in plane (tx>>1), local offset (tx&1)*8
    int plane = tx >> 1;
    int lo = (tx & 1) * 8;
    float* ob = HHc + (size_t)plane * PS + lo;
    #pragma unroll
    for (int i = 0; i < 8; ++i) {
        int grow = bm + ty * 8 + i;
        if (grow < M) {
            float di = scale[grow];
            vflt4 o0, o1;
            o0.x = acc[i][0] * di; o0.y = acc[i][1] * di;
            o0.z = acc[i][2] * di; o0.w = acc[i][3] * di;
            o1.x = acc[i][4] * di; o1.y = acc[i][5] * di;
            o1.z = acc[i][6] * di; o1.w = acc[i][7] * di;
            *(vflt4*)(ob + (size_t)grow * 16)     = o0;
            *(vflt4*)(ob + (size_t)grow * 16 + 4) = o1;
        }
    }
}

// ---------------- SpMM aggregate, feature-chunked, XCD-bound ----------------
// chunk = blockIdx & 7  -> one feature plane per XCD (round-robin dispatch heuristic).
// 16 lanes per node, scalar float per lane; gathers hit the XCD's 6.4 MB plane.
// FINAL=0: write chunked ACT planes; FINAL=1: write row-major out.

template<int FINAL>
__global__ __launch_bounds__(256) void k_spmm(const float* __restrict__ HHc,
                                              const int* __restrict__ colx,
                                              const int* __restrict__ rptr,
                                              const float* __restrict__ dinv,
                                              const float* __restrict__ bias,
                                              float* __restrict__ actD,
                                              float* __restrict__ actS,
                                              float* __restrict__ out,
                                              int n, size_t PS, int do_relu) {
    int chunk = blockIdx.x & 7;
    int node  = (blockIdx.x >> 3) * 16 + (threadIdx.x >> 4);
    int ll    = threadIdx.x & 15;
    if (node >= n) return;
    const float* plane = HHc + (size_t)chunk * PS;
    int e  = rptr[node];
    int e1 = rptr[node + 1];
    float acc = 0.f;
    #pragma unroll 2
    for (; e < e1; e += 4) {
        vint4 s = *(const vint4*)(colx + e);
        float h0 = plane[(size_t)s.x * 16 + ll];
        float h1 = plane[(size_t)s.y * 16 + ll];
        float h2 = plane[(size_t)s.z * 16 + ll];
        float h3 = plane[(size_t)s.w * 16 + ll];
        acc += (h0 + h1) + (h2 + h3);
    }
    float o = fmaf(dinv[node], acc, bias[chunk * 16 + ll]);
    if (do_relu) o = fmaxf(o, 0.f);
    if (FINAL) {
        out[(size_t)node * 128 + chunk * 16 + ll] = o;
    } else {
        float* ob = (chunk < 7) ? (actD + (size_t)chunk * PS) : actS;
        ob[(size_t)node * 16 + ll] = o;
    }
}

// ---------------- host ----------------

extern "C" void kernel_launch(void* const* d_in, const int* in_sizes, int n_in,
                              void* d_out, int out_size, void* d_ws, size_t ws_size,
                              hipStream_t stream) {
    const float* x  = (const float*)d_in[0];
    const int*   ei = (const int*)d_in[1];
    const float* W1 = (const float*)d_in[2];
    const float* b1 = (const float*)d_in[3];
    const float* W2 = (const float*)d_in[4];
    const float* b2 = (const float*)d_in[5];
    const float* W3 = (const float*)d_in[6];
    const float* b3 = (const float*)d_in[7];
    float* out = (float*)d_out;

    const int n = in_sizes[0] / N_HID;       // 100000
    const int E = in_sizes[1] / 2;           // 1600000
    const long T = (long)E + n;
    const size_t PS = (size_t)(n + 1) * 16;  // plane stride (floats)

    const int* src = ei;
    const int* dst = ei + E;

    size_t off = 0;
    auto alloc = [&](size_t bytes) {
        size_t o = off;
        off += (bytes + 255) & ~(size_t)255;
        return (char*)d_ws + o;
    };
    float* dinv   = (float*)alloc((size_t)n * 4);
    int*   rptr   = (int*)  alloc((size_t)(n + 1) * 4);
    int*   lofs   = (int*)  alloc((size_t)n * 4);
    int*   gcount = (int*)  alloc(1024);
    int*   gbase0 = (int*)  alloc(1024);
    int*   gcur   = (int*)  alloc(1024);
    int*   psum   = (int*)  alloc(1024);
    int*   pbase  = (int*)  alloc(1024);
    int*   colx   = (int*)  alloc((size_t)(T + 3 * (size_t)n + 64) * 4);
    float* actS   = (float*)alloc(PS * 4);           // ACT spill plane (chunk 7)
    float* HHc    = (float*)alloc(PS * 8 * 4);       // chunked GEMM output, 8 planes
    // bpair (u32, 6.8 MB) aliases HHc front (consumed by k_bfill before gemm1)
    unsigned* bpair = (unsigned*)HHc;
    float* actD = out;                                // ACT planes 0-6 staged in d_out
    (void)ws_size;

    const int NBK  = (n + BNODES - 1) >> BSH;          // 196 buckets
    const int ABLK = (int)((T + CHUNK - 1) / CHUNK);   // 416 chunks

    k_init<<<3, 256, 0, stream>>>(gcount, NBK, HHc, actD, actS, n, PS);
    k_bcount<<<ABLK, 256, 0, stream>>>(dst, E, n, gcount);
    k_bscan<<<1, 256, 0, stream>>>(gcount, gbase0, gcur, NBK);
    k_bucket<<<ABLK, 256, 0, stream>>>(src, dst, E, n, gcur, bpair);
    k_bdeg<<<NBK, 256, 0, stream>>>(bpair, gbase0, gcount, dinv, lofs, psum, n);
    k_pscan<<<1, 256, 0, stream>>>(psum, pbase, rptr, n, NBK);
    k_bfill<<<NBK, 256, 0, stream>>>(bpair, gbase0, gcount, pbase, lofs, psum, rptr, colx, n);
    // re-zero HHc dummy rows (bpair alias may have clobbered them)
    k_init<<<3, 256, 0, stream>>>(gcount, 0, HHc, actD, actS, n, PS);

    int gblk = (n + 127) / 128;
    int sblk = 8 * ((n + 15) / 16);   // 8 feature-chunks x node groups of 16

    k_gemm<0><<<gblk, 256, 0, stream>>>(x, nullptr, nullptr, W1, dinv, HHc, n, PS);
    k_spmm<0><<<sblk, 256, 0, stream>>>(HHc, colx, rptr, dinv, b1, actD, actS, out, n, PS, 1);
    k_gemm<1><<<gblk, 256, 0, stream>>>(nullptr, actD, actS, W2, dinv, HHc, n, PS);
    k_spmm<0><<<sblk, 256, 0, stream>>>(HHc, colx, rptr, dinv, b2, actD, actS, out, n, PS, 1);
    k_gemm<1><<<gblk, 256, 0, stream>>>(nullptr, actD, actS, W3, dinv, HHc, n, PS);
    k_spmm<1><<<sblk, 256, 0, stream>>>(HHc, colx, rptr, dinv, b3, actD, actS, out, n, PS, 0);
}